// Round 14
// baseline (124.433 us; speedup 1.0000x reference)
//
#include <hip/hip_runtime.h>
#include <hip/hip_fp16.h>

#define H 128
#define KSLOT 64   // dense bucket capacity per node (P(deg>64) ~ 1e-24 at lambda=12.8)

typedef __attribute__((ext_vector_type(8))) short bf8;     // 8 x bf16 (4 VGPRs)
typedef __attribute__((ext_vector_type(8))) unsigned short u16x8;
typedef __attribute__((ext_vector_type(4))) float f32x4;

__device__ __forceinline__ unsigned short f2bf(float f) {  // RNE f32 -> bf16
    unsigned u = __float_as_uint(f);
    return (unsigned short)((u + 0x7FFFu + ((u >> 16) & 1u)) >> 16);
}
__device__ __forceinline__ float bf2f(unsigned short b) {
    return __uint_as_float(((unsigned)b) << 16);
}

// ---------- prep: z->bf16; transposed bf16 weights; zero cnt; -inf sentinel ----------
// grid covers N*H/8 threads (largest role)
__global__ __launch_bounds__(256) void prep(
    const float* __restrict__ z, const float* __restrict__ Wmsg, const float* __restrict__ Wupd,
    unsigned short* __restrict__ zb,    // [Npad][128] bf16
    unsigned short* __restrict__ WmT,   // [256 outcol][128 k]
    unsigned short* __restrict__ WuT,   // [128 outcol][256 k]
    int* __restrict__ cnt,              // [N]
    unsigned short* __restrict__ ZS,    // sentinel row N = bf16 -inf
    int N)
{
    const int t = blockIdx.x * 256 + threadIdx.x;
    if (t < ((N + 3) >> 2)) ((int4*)cnt)[t] = make_int4(0, 0, 0, 0);  // may spill <=3 ints into ew: harmless pre-scatter
    const int zi = t * 8;
    if (zi < N * H) {  // z -> bf16
        const float4* p = (const float4*)(z + zi);
        float4 v0 = p[0], v1 = p[1];
        ushort4 o0, o1;
        o0.x = f2bf(v0.x); o0.y = f2bf(v0.y); o0.z = f2bf(v0.z); o0.w = f2bf(v0.w);
        o1.x = f2bf(v1.x); o1.y = f2bf(v1.y); o1.z = f2bf(v1.z); o1.w = f2bf(v1.w);
        ushort4* q = (ushort4*)(zb + zi);
        q[0] = o0; q[1] = o1;
    }
    if (t < 16) {
        u16x8 s;
#pragma unroll
        for (int i = 0; i < 8; ++i) s[i] = 0xFF80;  // -inf bf16
        *(u16x8*)(ZS + (size_t)N * H + t * 8) = s;
    }
    if (t < 256 * H) {  // WmT
        const int c = t >> 7, k = t & 127;
        WmT[t] = f2bf(Wmsg[(size_t)(k + (c & 128)) * H + (c & 127)]);
    }
    if (t < H * 256) {  // WuT
        const int c = t >> 8, k = t & 255;
        WuT[t] = f2bf(Wupd[(size_t)k * H + c]);
    }
}

// ---------- fused: blocks [0,ngemm) GEMM1 (bf16 A); blocks >= ngemm: edge scatter ----------
// 4B edge record: src(low16) | w_fp16(high16)
__global__ __launch_bounds__(256) void gemm1_scatter(
    const unsigned short* __restrict__ zb,   // [Npad][128] bf16
    const unsigned short* __restrict__ WmT,  // [256][128]
    unsigned short* __restrict__ ZS,         // [Npad+][128] bf16
    unsigned short* __restrict__ ZD,         // [Npad][128] bf16
    const int* __restrict__ src, const int* __restrict__ dst,
    const float* __restrict__ wgt, int* __restrict__ cnt,
    unsigned* __restrict__ ew,
    int N, int E, int ntiles, int ngemm)
{
    if ((int)blockIdx.x >= ngemm) {
        const int base = (blockIdx.x - ngemm) * 1024 + threadIdx.x;
        int dv[4]; unsigned rv[4]; bool ok[4];
#pragma unroll
        for (int k = 0; k < 4; ++k) {
            const int e = base + k * 256;
            ok[k] = e < E;
            const int ec = ok[k] ? e : 0;
            dv[k] = dst[ec];
            const unsigned short wh = __half_as_ushort(__float2half(wgt[ec]));
            rv[k] = (unsigned)(src[ec] & 0xFFFF) | ((unsigned)wh << 16);
        }
#pragma unroll
        for (int k = 0; k < 4; ++k) {
            if (ok[k]) {
                int p = atomicAdd(&cnt[dv[k]], 1);
                if (p < KSLOT) ew[((size_t)dv[k] << 6) + p] = rv[k];
            }
        }
        return;
    }
    const int l = threadIdx.x & 63;
    const int w = threadIdx.x >> 6;
    const int r = l & 15, g = l >> 4;
    const int colbase = w * 64;
    unsigned short* Out = (w < 2) ? ZS : ZD;
    const int outcol = colbase & 127;

    bf8 wf[4][4];
#pragma unroll
    for (int nf = 0; nf < 4; ++nf)
#pragma unroll
        for (int kk = 0; kk < 4; ++kk)
            wf[kk][nf] = *(const bf8*)(WmT + (size_t)(colbase + nf * 16 + r) * H + kk * 32 + g * 8);

    const f32x4 zero = {0.f, 0.f, 0.f, 0.f};
    for (int tt = blockIdx.x; tt < ntiles; tt += ngemm) {
        const int row0 = tt * 32;
#pragma unroll
        for (int m = 0; m < 2; ++m) {
            const int node = row0 + m * 16 + r;
            const int rowc = node < N ? node : N - 1;
            bf8 zf[4];
#pragma unroll
            for (int kk = 0; kk < 4; ++kk)
                zf[kk] = *(const bf8*)(zb + (size_t)rowc * H + kk * 32 + g * 8);
            f32x4 acc[4] = {zero, zero, zero, zero};
#pragma unroll
            for (int kk = 0; kk < 4; ++kk)
#pragma unroll
                for (int nf = 0; nf < 4; ++nf)
                    acc[nf] = __builtin_amdgcn_mfma_f32_16x16x32_bf16(wf[kk][nf], zf[kk], acc[nf], 0, 0, 0);
            if (node < N) {
#pragma unroll
                for (int nf = 0; nf < 4; ++nf) {
                    ushort4 o;
                    o.x = f2bf(acc[nf][0]); o.y = f2bf(acc[nf][1]);
                    o.z = f2bf(acc[nf][2]); o.w = f2bf(acc[nf][3]);
                    *(ushort4*)(Out + (size_t)node * H + outcol + nf * 16 + g * 4) = o;
                }
            }
        }
    }
}

// ---------- aggregate (wave-per-node, dense buckets, 4 independent gather chains) ----------
// 4 waves/block = 4 nodes; lane = (sub 0..3) x (c16 0..15); slots j*16+sub+{0,4,8,12}.
__global__ __launch_bounds__(256) void aggregate(
    const unsigned short* __restrict__ ZS,   // [Npad+][128] bf16 (+ sentinel row N = -inf)
    const unsigned short* __restrict__ ZD,   // [Npad][128] bf16
    unsigned short* __restrict__ Agg,        // [Npad][128] bf16 out
    const float* __restrict__ bmsg, const float* __restrict__ wrow,
    const int* __restrict__ cnt, const unsigned* __restrict__ ew, int N)
{
    const int node = blockIdx.x * 4 + (threadIdx.x >> 6);
    if (node >= N) return;
    const int l = threadIdx.x & 63;
    const int sub = l >> 4;
    const int c16 = l & 15;

    const int d = min(cnt[node], KSLOT);
    const int iters = (d + 15) >> 4;

    float wr[8];
    {
        float4 w0 = *(const float4*)(wrow + c16 * 8);
        float4 w1 = *(const float4*)(wrow + c16 * 8 + 4);
        wr[0] = w0.x; wr[1] = w0.y; wr[2] = w0.z; wr[3] = w0.w;
        wr[4] = w1.x; wr[5] = w1.y; wr[6] = w1.z; wr[7] = w1.w;
    }

    const float NINF = -__builtin_inff();
    float m[8];
#pragma unroll
    for (int i = 0; i < 8; ++i) m[i] = NINF;

    const unsigned* ep = ew + ((size_t)node << 6) + sub;
    for (int j = 0; j < iters; ++j) {
        const int s0 = j * 16 + sub;
        const unsigned e0 = ep[j * 16];
        const unsigned e1 = ep[j * 16 + 4];
        const unsigned e2 = ep[j * 16 + 8];
        const unsigned e3 = ep[j * 16 + 12];
        const int r0 = (s0      < d) ? (int)(e0 & 0xFFFF) : N;
        const int r1 = (s0 + 4  < d) ? (int)(e1 & 0xFFFF) : N;
        const int r2 = (s0 + 8  < d) ? (int)(e2 & 0xFFFF) : N;
        const int r3 = (s0 + 12 < d) ? (int)(e3 & 0xFFFF) : N;
        const float w0 = (s0      < d) ? __half2float(__ushort_as_half((unsigned short)(e0 >> 16))) : 0.f;
        const float w1 = (s0 + 4  < d) ? __half2float(__ushort_as_half((unsigned short)(e1 >> 16))) : 0.f;
        const float w2 = (s0 + 8  < d) ? __half2float(__ushort_as_half((unsigned short)(e2 >> 16))) : 0.f;
        const float w3 = (s0 + 12 < d) ? __half2float(__ushort_as_half((unsigned short)(e3 >> 16))) : 0.f;
        u16x8 v0 = *(const u16x8*)(ZS + (size_t)r0 * H + c16 * 8);
        u16x8 v1 = *(const u16x8*)(ZS + (size_t)r1 * H + c16 * 8);
        u16x8 v2 = *(const u16x8*)(ZS + (size_t)r2 * H + c16 * 8);
        u16x8 v3 = *(const u16x8*)(ZS + (size_t)r3 * H + c16 * 8);
#pragma unroll
        for (int i = 0; i < 8; ++i) {
            const float a = fmaxf(__builtin_fmaf(w0, wr[i], bf2f((unsigned short)v0[i])),
                                  __builtin_fmaf(w1, wr[i], bf2f((unsigned short)v1[i])));
            const float b = fmaxf(__builtin_fmaf(w2, wr[i], bf2f((unsigned short)v2[i])),
                                  __builtin_fmaf(w3, wr[i], bf2f((unsigned short)v3[i])));
            m[i] = fmaxf(m[i], fmaxf(a, b));
        }
    }
#pragma unroll
    for (int i = 0; i < 8; ++i) {
        m[i] = fmaxf(m[i], __shfl_xor(m[i], 16));
        m[i] = fmaxf(m[i], __shfl_xor(m[i], 32));
    }

    if (sub == 0) {
        u16x8 zd = *(const u16x8*)(ZD + (size_t)node * H + c16 * 8);
        float bm[8];
        float4 b0 = *(const float4*)(bmsg + c16 * 8);
        float4 b1 = *(const float4*)(bmsg + c16 * 8 + 4);
        bm[0] = b0.x; bm[1] = b0.y; bm[2] = b0.z; bm[3] = b0.w;
        bm[4] = b1.x; bm[5] = b1.y; bm[6] = b1.z; bm[7] = b1.w;
        u16x8 o;
#pragma unroll
        for (int i = 0; i < 8; ++i) {
            float r = (d > 0) ? (m[i] + bf2f((unsigned short)zd[i]) + bm[i]) : 0.f;
            o[i] = f2bf(r);
        }
        *(u16x8*)(Agg + (size_t)node * H + c16 * 8) = o;
    }
}

// ---------- GEMM2: out = [zb | Agg] @ Wupd + bupd (f32 out); one 32-row tile per block ----------
__global__ __launch_bounds__(256) void gemm_upd_mfma(
    const unsigned short* __restrict__ zb,   // [Npad][128] bf16
    const unsigned short* __restrict__ Agg,  // [Npad][128] bf16
    const unsigned short* __restrict__ WuT,  // [128][256]
    const float* __restrict__ bupd,
    float* __restrict__ out, int N)
{
    const int l = threadIdx.x & 63;
    const int w = threadIdx.x >> 6;
    const int r = l & 15, g = l >> 4;
    const int colbase = w * 32;

    bf8 wf[8][2];
#pragma unroll
    for (int nf = 0; nf < 2; ++nf)
#pragma unroll
        for (int kk = 0; kk < 8; ++kk)
            wf[kk][nf] = *(const bf8*)(WuT + (size_t)(colbase + nf * 16 + r) * 256 + kk * 32 + g * 8);
    float4 bias[2];
#pragma unroll
    for (int nf = 0; nf < 2; ++nf)
        bias[nf] = *(const float4*)(bupd + colbase + nf * 16 + g * 4);

    const f32x4 zero = {0.f, 0.f, 0.f, 0.f};
    const int row0 = blockIdx.x * 32;
#pragma unroll
    for (int m = 0; m < 2; ++m) {
        const int node = row0 + m * 16 + r;
        const int rowc = node < N ? node : N - 1;
        bf8 zf[8];
#pragma unroll
        for (int kk = 0; kk < 4; ++kk)
            zf[kk] = *(const bf8*)(zb + (size_t)rowc * H + kk * 32 + g * 8);
#pragma unroll
        for (int kk = 4; kk < 8; ++kk)
            zf[kk] = *(const bf8*)(Agg + (size_t)rowc * H + (kk - 4) * 32 + g * 8);
        f32x4 acc[2] = {zero, zero};
#pragma unroll
        for (int kk = 0; kk < 8; ++kk)
#pragma unroll
            for (int nf = 0; nf < 2; ++nf)
                acc[nf] = __builtin_amdgcn_mfma_f32_16x16x32_bf16(wf[kk][nf], zf[kk], acc[nf], 0, 0, 0);
        if (node < N) {
#pragma unroll
            for (int nf = 0; nf < 2; ++nf) {
                float4 o;
                o.x = acc[nf][0] + bias[nf].x;
                o.y = acc[nf][1] + bias[nf].y;
                o.z = acc[nf][2] + bias[nf].z;
                o.w = acc[nf][3] + bias[nf].w;
                *(float4*)(out + (size_t)node * H + colbase + nf * 16 + g * 4) = o;
            }
        }
    }
}

extern "C" void kernel_launch(void* const* d_in, const int* in_sizes, int n_in,
                              void* d_out, int out_size, void* d_ws, size_t ws_size,
                              hipStream_t stream) {
    const float* z    = (const float*)d_in[0];
    const int*   src  = (const int*)d_in[1];
    const int*   dst  = (const int*)d_in[2];
    const float* wgt  = (const float*)d_in[3];
    const float* Wmsg = (const float*)d_in[4];   // [257][128]
    const float* bmsg = (const float*)d_in[5];
    const float* Wupd = (const float*)d_in[6];   // [256][128]
    const float* bupd = (const float*)d_in[7];
    float* out = (float*)d_out;

    const int N = in_sizes[0] / H;            // 50000 (< 65536: fits 16-bit src packing)
    const int E = in_sizes[1];                // 640000
    const int Npad = ((N + 31) / 32) * 32;    // 50016
    const int ntiles = Npad / 32;             // 1563

    // ws layout
    unsigned short* zb  = (unsigned short*)d_ws;            // [Npad][128] bf16
    unsigned short* ZS  = zb + (size_t)Npad * H;            // [Npad+32][128] (row N = -inf sentinel)
    unsigned short* ZD  = ZS + (size_t)(Npad + 32) * H;     // [Npad][128]
    unsigned short* Agg = ZD + (size_t)Npad * H;            // [Npad][128]
    unsigned short* WmT = Agg + (size_t)Npad * H;           // 256*128
    unsigned short* WuT = WmT + 256 * H;                    // 128*256
    int*      cnt = (int*)(WuT + H * 256);                  // N
    unsigned* ew  = (unsigned*)(cnt + ((N + 3) & ~3));      // N * KSLOT 4B records

    const int ngemm = 784;
    const int nscat = (E + 1023) / 1024;                    // 4 edges/thread
    const int nprep = (N * H / 8 + 255) / 256;

    prep<<<nprep, 256, 0, stream>>>(z, Wmsg, Wupd, zb, WmT, WuT, cnt, ZS, N);

    gemm1_scatter<<<ngemm + nscat, 256, 0, stream>>>(
        zb, WmT, ZS, ZD, src, dst, wgt, cnt, ew, N, E, ntiles, ngemm);

    aggregate<<<(N + 3) / 4, 256, 0, stream>>>(
        ZS, ZD, Agg, bmsg, Wmsg + (size_t)256 * H, cnt, ew, N);

    gemm_upd_mfma<<<ntiles, 256, 0, stream>>>(zb, Agg, WuT, bupd, out, N);
}

// Round 15
// 117.308 us; speedup vs baseline: 1.0607x; 1.0607x over previous
//
#include <hip/hip_runtime.h>

#define H 128
#define KSLOT 64   // dense bucket capacity per node (P(deg>64) ~ 1e-24 at lambda=12.8)
#define CSTRIDE 16 // cnt: one counter per 64B line

typedef __attribute__((ext_vector_type(8))) short bf8;     // 8 x bf16 (4 VGPRs)
typedef __attribute__((ext_vector_type(8))) unsigned short u16x8;
typedef __attribute__((ext_vector_type(4))) float f32x4;

__device__ __forceinline__ unsigned short f2bf(float f) {  // RNE f32 -> bf16
    unsigned u = __float_as_uint(f);
    return (unsigned short)((u + 0x7FFFu + ((u >> 16) & 1u)) >> 16);
}
__device__ __forceinline__ float bf2f(unsigned short b) {
    return __uint_as_float(((unsigned)b) << 16);
}

// ---------- prep: z->bf16; transposed bf16 weights; zero cnt; -inf sentinel ----------
// grid covers max(N*H/8, N*CSTRIDE/4) threads
__global__ __launch_bounds__(256) void prep(
    const float* __restrict__ z, const float* __restrict__ Wmsg, const float* __restrict__ Wupd,
    unsigned short* __restrict__ zb,    // [Npad][128] bf16
    unsigned short* __restrict__ WmT,   // [256 outcol][128 k]
    unsigned short* __restrict__ WuT,   // [128 outcol][256 k]
    int* __restrict__ cnt,              // [N*CSTRIDE]
    unsigned short* __restrict__ ZS,    // sentinel row N = bf16 -inf
    int N)
{
    const int t = blockIdx.x * 256 + threadIdx.x;
    const int n4 = (N * CSTRIDE) >> 2;
    if (t < n4) ((int4*)cnt)[t] = make_int4(0, 0, 0, 0);
    const int zi = t * 8;
    if (zi < N * H) {  // z -> bf16
        const float4* p = (const float4*)(z + zi);
        float4 v0 = p[0], v1 = p[1];
        ushort4 o0, o1;
        o0.x = f2bf(v0.x); o0.y = f2bf(v0.y); o0.z = f2bf(v0.z); o0.w = f2bf(v0.w);
        o1.x = f2bf(v1.x); o1.y = f2bf(v1.y); o1.z = f2bf(v1.z); o1.w = f2bf(v1.w);
        ushort4* q = (ushort4*)(zb + zi);
        q[0] = o0; q[1] = o1;
    }
    if (t < 16) {
        u16x8 s;
#pragma unroll
        for (int i = 0; i < 8; ++i) s[i] = 0xFF80;  // -inf bf16
        *(u16x8*)(ZS + (size_t)N * H + t * 8) = s;
    }
    if (t < 256 * H) {  // WmT
        const int c = t >> 7, k = t & 127;
        WmT[t] = f2bf(Wmsg[(size_t)(k + (c & 128)) * H + (c & 127)]);
    }
    if (t < H * 256) {  // WuT
        const int c = t >> 8, k = t & 255;
        WuT[t] = f2bf(Wupd[(size_t)k * H + c]);
    }
}

// ---------- fused: blocks [0,ngemm) GEMM1 (bf16 A); blocks >= ngemm: edge scatter ----------
__global__ __launch_bounds__(256) void gemm1_scatter(
    const unsigned short* __restrict__ zb,   // [Npad][128] bf16
    const unsigned short* __restrict__ WmT,  // [256][128]
    unsigned short* __restrict__ ZS,         // [Npad+][128] bf16
    unsigned short* __restrict__ ZD,         // [Npad][128] bf16
    const int* __restrict__ src, const int* __restrict__ dst,
    const float* __restrict__ wgt, int* __restrict__ cnt,
    int2* __restrict__ ew,
    int N, int E, int ntiles, int ngemm)
{
    if ((int)blockIdx.x >= ngemm) {
        const int base = (blockIdx.x - ngemm) * 1024 + threadIdx.x;
        int dv[4], sv[4]; float wv[4]; bool ok[4];
#pragma unroll
        for (int k = 0; k < 4; ++k) {
            const int e = base + k * 256;
            ok[k] = e < E;
            const int ec = ok[k] ? e : 0;
            dv[k] = dst[ec]; sv[k] = src[ec]; wv[k] = wgt[ec];
        }
#pragma unroll
        for (int k = 0; k < 4; ++k) {
            if (ok[k]) {
                int p = atomicAdd(&cnt[(size_t)dv[k] * CSTRIDE], 1);
                if (p < KSLOT)
                    ew[((size_t)dv[k] << 6) + p] = make_int2(sv[k], __float_as_int(wv[k]));
            }
        }
        return;
    }
    const int l = threadIdx.x & 63;
    const int w = threadIdx.x >> 6;
    const int r = l & 15, g = l >> 4;
    const int colbase = w * 64;
    unsigned short* Out = (w < 2) ? ZS : ZD;
    const int outcol = colbase & 127;

    bf8 wf[4][4];
#pragma unroll
    for (int nf = 0; nf < 4; ++nf)
#pragma unroll
        for (int kk = 0; kk < 4; ++kk)
            wf[kk][nf] = *(const bf8*)(WmT + (size_t)(colbase + nf * 16 + r) * H + kk * 32 + g * 8);

    const f32x4 zero = {0.f, 0.f, 0.f, 0.f};
    for (int tt = blockIdx.x; tt < ntiles; tt += ngemm) {
        const int row0 = tt * 32;
#pragma unroll
        for (int m = 0; m < 2; ++m) {
            const int node = row0 + m * 16 + r;
            const int rowc = node < N ? node : N - 1;
            bf8 zf[4];
#pragma unroll
            for (int kk = 0; kk < 4; ++kk)
                zf[kk] = *(const bf8*)(zb + (size_t)rowc * H + kk * 32 + g * 8);
            f32x4 acc[4] = {zero, zero, zero, zero};
#pragma unroll
            for (int kk = 0; kk < 4; ++kk)
#pragma unroll
                for (int nf = 0; nf < 4; ++nf)
                    acc[nf] = __builtin_amdgcn_mfma_f32_16x16x32_bf16(wf[kk][nf], zf[kk], acc[nf], 0, 0, 0);
            if (node < N) {
#pragma unroll
                for (int nf = 0; nf < 4; ++nf) {
                    ushort4 o;
                    o.x = f2bf(acc[nf][0]); o.y = f2bf(acc[nf][1]);
                    o.z = f2bf(acc[nf][2]); o.w = f2bf(acc[nf][3]);
                    *(ushort4*)(Out + (size_t)node * H + outcol + nf * 16 + g * 4) = o;
                }
            }
        }
    }
}

// ---------- aggregate (wave-per-node, dense buckets, 4 independent gather chains) ----------
// 4 waves/block = 4 nodes; lane = (sub 0..3) x (c16 0..15); slots j*16+sub+{0,4,8,12}.
__global__ __launch_bounds__(256) void aggregate(
    const unsigned short* __restrict__ ZS,   // [Npad+][128] bf16 (+ sentinel row N = -inf)
    const unsigned short* __restrict__ ZD,   // [Npad][128] bf16
    unsigned short* __restrict__ Agg,        // [Npad][128] bf16 out
    const float* __restrict__ bmsg, const float* __restrict__ wrow,
    const int* __restrict__ cnt, const int2* __restrict__ ew, int N)
{
    const int node = blockIdx.x * 4 + (threadIdx.x >> 6);
    if (node >= N) return;
    const int l = threadIdx.x & 63;
    const int sub = l >> 4;
    const int c16 = l & 15;

    const int d = min(cnt[(size_t)node * CSTRIDE], KSLOT);
    const int iters = (d + 15) >> 4;

    float wr[8];
    {
        float4 w0 = *(const float4*)(wrow + c16 * 8);
        float4 w1 = *(const float4*)(wrow + c16 * 8 + 4);
        wr[0] = w0.x; wr[1] = w0.y; wr[2] = w0.z; wr[3] = w0.w;
        wr[4] = w1.x; wr[5] = w1.y; wr[6] = w1.z; wr[7] = w1.w;
    }

    const float NINF = -__builtin_inff();
    float m[8];
#pragma unroll
    for (int i = 0; i < 8; ++i) m[i] = NINF;

    const int2* ep = ew + ((size_t)node << 6) + sub;
    for (int j = 0; j < iters; ++j) {
        const int s0 = j * 16 + sub;
        int2 e0 = ep[j * 16];
        int2 e1 = ep[j * 16 + 4];
        int2 e2 = ep[j * 16 + 8];
        int2 e3 = ep[j * 16 + 12];
        const int r0 = (s0      < d) ? e0.x : N;
        const int r1 = (s0 + 4  < d) ? e1.x : N;
        const int r2 = (s0 + 8  < d) ? e2.x : N;
        const int r3 = (s0 + 12 < d) ? e3.x : N;
        const float w0 = (s0      < d) ? __int_as_float(e0.y) : 0.f;
        const float w1 = (s0 + 4  < d) ? __int_as_float(e1.y) : 0.f;
        const float w2 = (s0 + 8  < d) ? __int_as_float(e2.y) : 0.f;
        const float w3 = (s0 + 12 < d) ? __int_as_float(e3.y) : 0.f;
        u16x8 v0 = *(const u16x8*)(ZS + (size_t)r0 * H + c16 * 8);
        u16x8 v1 = *(const u16x8*)(ZS + (size_t)r1 * H + c16 * 8);
        u16x8 v2 = *(const u16x8*)(ZS + (size_t)r2 * H + c16 * 8);
        u16x8 v3 = *(const u16x8*)(ZS + (size_t)r3 * H + c16 * 8);
#pragma unroll
        for (int i = 0; i < 8; ++i) {
            const float a = fmaxf(__builtin_fmaf(w0, wr[i], bf2f((unsigned short)v0[i])),
                                  __builtin_fmaf(w1, wr[i], bf2f((unsigned short)v1[i])));
            const float b = fmaxf(__builtin_fmaf(w2, wr[i], bf2f((unsigned short)v2[i])),
                                  __builtin_fmaf(w3, wr[i], bf2f((unsigned short)v3[i])));
            m[i] = fmaxf(m[i], fmaxf(a, b));
        }
    }
#pragma unroll
    for (int i = 0; i < 8; ++i) {
        m[i] = fmaxf(m[i], __shfl_xor(m[i], 16));
        m[i] = fmaxf(m[i], __shfl_xor(m[i], 32));
    }

    if (sub == 0) {
        u16x8 zd = *(const u16x8*)(ZD + (size_t)node * H + c16 * 8);
        float bm[8];
        float4 b0 = *(const float4*)(bmsg + c16 * 8);
        float4 b1 = *(const float4*)(bmsg + c16 * 8 + 4);
        bm[0] = b0.x; bm[1] = b0.y; bm[2] = b0.z; bm[3] = b0.w;
        bm[4] = b1.x; bm[5] = b1.y; bm[6] = b1.z; bm[7] = b1.w;
        u16x8 o;
#pragma unroll
        for (int i = 0; i < 8; ++i) {
            float r = (d > 0) ? (m[i] + bf2f((unsigned short)zd[i]) + bm[i]) : 0.f;
            o[i] = f2bf(r);
        }
        *(u16x8*)(Agg + (size_t)node * H + c16 * 8) = o;
    }
}

// ---------- GEMM2: out = [zb | Agg] @ Wupd + bupd (f32 out), all-bf16 A loads ----------
__global__ __launch_bounds__(256) void gemm_upd_mfma(
    const unsigned short* __restrict__ zb,   // [Npad][128] bf16
    const unsigned short* __restrict__ Agg,  // [Npad][128] bf16
    const unsigned short* __restrict__ WuT,  // [128][256]
    const float* __restrict__ bupd,
    float* __restrict__ out, int N, int ntiles)
{
    const int l = threadIdx.x & 63;
    const int w = threadIdx.x >> 6;
    const int r = l & 15, g = l >> 4;
    const int colbase = w * 32;

    bf8 wf[8][2];
#pragma unroll
    for (int nf = 0; nf < 2; ++nf)
#pragma unroll
        for (int kk = 0; kk < 8; ++kk)
            wf[kk][nf] = *(const bf8*)(WuT + (size_t)(colbase + nf * 16 + r) * 256 + kk * 32 + g * 8);
    float4 bias[2];
#pragma unroll
    for (int nf = 0; nf < 2; ++nf)
        bias[nf] = *(const float4*)(bupd + colbase + nf * 16 + g * 4);

    const f32x4 zero = {0.f, 0.f, 0.f, 0.f};
    for (int tt = blockIdx.x; tt < ntiles; tt += gridDim.x) {
        const int row0 = tt * 32;
#pragma unroll
        for (int m = 0; m < 2; ++m) {
            const int node = row0 + m * 16 + r;
            const int rowc = node < N ? node : N - 1;
            bf8 zf[8];
#pragma unroll
            for (int kk = 0; kk < 4; ++kk)
                zf[kk] = *(const bf8*)(zb + (size_t)rowc * H + kk * 32 + g * 8);
#pragma unroll
            for (int kk = 4; kk < 8; ++kk)
                zf[kk] = *(const bf8*)(Agg + (size_t)rowc * H + (kk - 4) * 32 + g * 8);
            f32x4 acc[2] = {zero, zero};
#pragma unroll
            for (int kk = 0; kk < 8; ++kk)
#pragma unroll
                for (int nf = 0; nf < 2; ++nf)
                    acc[nf] = __builtin_amdgcn_mfma_f32_16x16x32_bf16(wf[kk][nf], zf[kk], acc[nf], 0, 0, 0);
            if (node < N) {
#pragma unroll
                for (int nf = 0; nf < 2; ++nf) {
                    float4 o;
                    o.x = acc[nf][0] + bias[nf].x;
                    o.y = acc[nf][1] + bias[nf].y;
                    o.z = acc[nf][2] + bias[nf].z;
                    o.w = acc[nf][3] + bias[nf].w;
                    *(float4*)(out + (size_t)node * H + colbase + nf * 16 + g * 4) = o;
                }
            }
        }
    }
}

extern "C" void kernel_launch(void* const* d_in, const int* in_sizes, int n_in,
                              void* d_out, int out_size, void* d_ws, size_t ws_size,
                              hipStream_t stream) {
    const float* z    = (const float*)d_in[0];
    const int*   src  = (const int*)d_in[1];
    const int*   dst  = (const int*)d_in[2];
    const float* wgt  = (const float*)d_in[3];
    const float* Wmsg = (const float*)d_in[4];   // [257][128]
    const float* bmsg = (const float*)d_in[5];
    const float* Wupd = (const float*)d_in[6];   // [256][128]
    const float* bupd = (const float*)d_in[7];
    float* out = (float*)d_out;

    const int N = in_sizes[0] / H;            // 50000
    const int E = in_sizes[1];                // 640000
    const int Npad = ((N + 31) / 32) * 32;    // 50016
    const int ntiles = Npad / 32;             // 1563

    // ws layout
    unsigned short* zb  = (unsigned short*)d_ws;            // [Npad][128] bf16
    unsigned short* ZS  = zb + (size_t)Npad * H;            // [Npad+32][128] (row N = -inf sentinel)
    unsigned short* ZD  = ZS + (size_t)(Npad + 32) * H;     // [Npad][128]
    unsigned short* Agg = ZD + (size_t)Npad * H;            // [Npad][128]
    unsigned short* WmT = Agg + (size_t)Npad * H;           // 256*128
    unsigned short* WuT = WmT + 256 * H;                    // 128*256
    int*  cnt = (int*)(WuT + H * 256);                      // N * CSTRIDE
    int2* ew  = (int2*)(cnt + (size_t)N * CSTRIDE);         // N * KSLOT

    const int ngemm = 784;
    const int nscat = (E + 1023) / 1024;                    // 4 edges/thread
    const int nprep_threads = max(N * H / 8, (N * CSTRIDE) / 4);
    const int nprep = (nprep_threads + 255) / 256;

    prep<<<nprep, 256, 0, stream>>>(z, Wmsg, Wupd, zb, WmT, WuT, cnt, ZS, N);

    gemm1_scatter<<<ngemm + nscat, 256, 0, stream>>>(
        zb, WmT, ZS, ZD, src, dst, wgt, cnt, ew, N, E, ntiles, ngemm);

    aggregate<<<(N + 3) / 4, 256, 0, stream>>>(
        ZS, ZD, Agg, bmsg, Wmsg + (size_t)256 * H, cnt, ew, N);

    gemm_upd_mfma<<<784, 256, 0, stream>>>(zb, Agg, WuT, bupd, out, N, ntiles);
}